// Round 1
// baseline (385.646 us; speedup 1.0000x reference)
//
#include <hip/hip_runtime.h>
#include <math.h>

#define SEQ     512
#define RDIM    64
#define NWAVE   4
#define RING_D  8    // ring slots; vmcnt = 4*(RING_D-1) = 28

__device__ __forceinline__ void load_lds_16B(const float* g, float* l) {
    __builtin_amdgcn_global_load_lds(
        (const __attribute__((address_space(1))) void*)g,
        (__attribute__((address_space(3))) void*)l,
        16, 0, 0);
}

__global__ __launch_bounds__(256, 1)
void matchain_kernel(const int* __restrict__ input_ids,
                     const float* __restrict__ G_weight,
                     const float* __restrict__ G1_weight,
                     const float* __restrict__ lin_W,
                     const float* __restrict__ lin_b,
                     float* __restrict__ out)
{
    // 8 * 16KB ring + 1KB partial + 2KB ids = 131.25 KB LDS (1 wg/CU; only 64 wgs anyway)
    __shared__ float ring[RING_D * RDIM * RDIM];
    __shared__ float partial[NWAVE * RDIM];
    __shared__ int   ids[SEQ];

    const int tid  = threadIdx.x;
    const int lane = tid & 63;
    const int w    = tid >> 6;            // wave id 0..3
    const int b    = blockIdx.x;

    ids[tid]       = input_ids[b * SEQ + tid];
    ids[tid + 256] = input_ids[b * SEQ + tid + 256];
    __syncthreads();

    // init: v_j = G1_weight[j], replicated in every wave (lane j holds v[j])
    float vj = G1_weight[lane];

    // wave-uniform row base as SGPR for readlane
    const int wbase = __builtin_amdgcn_readfirstlane(w << 4);

    // prologue: prefetch steps 0..RING_D-2 (each wave stages floats [w*1024, w*1024+1024))
    for (int p = 0; p < RING_D - 1; ++p) {
        const int id   = ids[p];
        const float* g = G_weight + ((size_t)id << 12) + (w << 10) + (lane << 2);
        float*       l = &ring[(p << 12) + (w << 10)];
#pragma unroll
        for (int k = 0; k < 4; ++k)
            load_lds_16B(g + (k << 8), l + (k << 8));
    }

#pragma unroll 1
    for (int t = 0; t < SEQ; ++t) {
        // 1) issue prefetch for step t+RING_D-1 (clamped source keeps vmcnt bookkeeping uniform;
        //    tail "dummy" slots are provably never read)
        {
            const int p    = t + RING_D - 1;
            const int pc   = (p < SEQ) ? p : (SEQ - 1);
            const int id   = ids[pc];
            const int slot = p & (RING_D - 1);
            const float* g = G_weight + ((size_t)id << 12) + (w << 10) + (lane << 2);
            float*       l = &ring[(slot << 12) + (w << 10)];
#pragma unroll
            for (int k = 0; k < 4; ++k)
                load_lds_16B(g + (k << 8), l + (k << 8));
        }

        // 2) slot t valid once all but the newest 4*(RING_D-1) loads retire.
        //    lgkmcnt(0): our previous partial-reads must complete before the barrier
        //    so next iteration's partial writes can't race them.
        asm volatile("s_waitcnt vmcnt(28) lgkmcnt(0)\n\ts_barrier" ::: "memory");

        // 3) compute: wave w handles rows [16w, 16w+16); lane j owns column j
        const float* Ms = &ring[(size_t)(t & (RING_D - 1)) << 12];
        float acc0 = 0.f, acc1 = 0.f, acc2 = 0.f, acc3 = 0.f;
#pragma unroll
        for (int k = 0; k < 16; k += 4) {
            const float m0 = Ms[((wbase + k + 0) << 6) + lane];
            const float m1 = Ms[((wbase + k + 1) << 6) + lane];
            const float m2 = Ms[((wbase + k + 2) << 6) + lane];
            const float m3 = Ms[((wbase + k + 3) << 6) + lane];
            const float v0 = __int_as_float(__builtin_amdgcn_readlane(__float_as_int(vj), wbase + k + 0));
            const float v1 = __int_as_float(__builtin_amdgcn_readlane(__float_as_int(vj), wbase + k + 1));
            const float v2 = __int_as_float(__builtin_amdgcn_readlane(__float_as_int(vj), wbase + k + 2));
            const float v3 = __int_as_float(__builtin_amdgcn_readlane(__float_as_int(vj), wbase + k + 3));
            acc0 = fmaf(v0, m0, acc0);
            acc1 = fmaf(v1, m1, acc1);
            acc2 = fmaf(v2, m2, acc2);
            acc3 = fmaf(v3, m3, acc3);
        }
        const float pj = (acc0 + acc1) + (acc2 + acc3);

        partial[(w << 6) + lane] = pj;
        // partial writes must be LDS-complete before any wave reads them
        asm volatile("s_waitcnt lgkmcnt(0)\n\ts_barrier" ::: "memory");

        float nv = 0.f;
#pragma unroll
        for (int q = 0; q < NWAVE; ++q)
            nv += partial[(q << 6) + lane];
        vj = nv;   // replicated identically in all waves
    }

    // drain any dummy prefetches before waves retire
    asm volatile("s_waitcnt vmcnt(0)" ::: "memory");

    // epilogue on wave 0: normalize + (2x64) linear
    if (w == 0) {
        float s = vj * vj;
#pragma unroll
        for (int off = 32; off >= 1; off >>= 1)
            s += __shfl_xor(s, off, 64);
        const float inv = 1.0f / fmaxf(sqrtf(s), 1e-12f);
        const float nj  = vj * inv;

        float d0 = nj * lin_W[lane];
        float d1 = nj * lin_W[RDIM + lane];
#pragma unroll
        for (int off = 32; off >= 1; off >>= 1) {
            d0 += __shfl_xor(d0, off, 64);
            d1 += __shfl_xor(d1, off, 64);
        }
        if (lane == 0) {
            out[b * 2 + 0] = d0 + lin_b[0];
            out[b * 2 + 1] = d1 + lin_b[1];
        }
    }
}

extern "C" void kernel_launch(void* const* d_in, const int* in_sizes, int n_in,
                              void* d_out, int out_size, void* d_ws, size_t ws_size,
                              hipStream_t stream) {
    const int*   input_ids = (const int*)d_in[0];
    // d_in[1] = mask (all ones), d_in[2] = segment_ids, d_in[3] = seq_lengths — unused
    const float* G_weight  = (const float*)d_in[4];
    const float* G1_weight = (const float*)d_in[5];
    const float* lin_W     = (const float*)d_in[6];
    const float* lin_b     = (const float*)d_in[7];
    float*       out       = (float*)d_out;

    matchain_kernel<<<64, 256, 0, stream>>>(input_ids, G_weight, G1_weight, lin_W, lin_b, out);
}

// Round 2
// 221.273 us; speedup vs baseline: 1.7428x; 1.7428x over previous
//
#include <hip/hip_runtime.h>
#include <math.h>

#define SEQ   512
#define RDIM  64
#define NW    8     // waves per block (512 threads)
#define PF    8     // register prefetch depth (steps ahead)

__global__ __launch_bounds__(512, 1)
void matchain_kernel(const int* __restrict__ input_ids,
                     const float* __restrict__ G_weight,
                     const float* __restrict__ G1_weight,
                     const float* __restrict__ lin_W,
                     const float* __restrict__ lin_b,
                     float* __restrict__ out)
{
    __shared__ int   ids[SEQ];
    __shared__ float partial[2][NW * RDIM];   // double-buffered: 1 barrier/step

    const int tid  = threadIdx.x;
    const int lane = tid & 63;
    const int w    = tid >> 6;           // wave 0..7
    const int b    = blockIdx.x;
    const int rq   = lane >> 4;          // 0..3 : which of 4 rows in each chunk

    ids[tid] = input_ids[b * SEQ + tid]; // 512 threads cover 512 ids
    __syncthreads();

    // v replicated in every wave: lane j holds v[j]
    float vj = G1_weight[lane];

    // wave w owns rows [8w, 8w+8): chunk0 = rows 8w..8w+3, chunk1 = rows 8w+4..8w+7
    // lane i, chunk h holds M[8w + 4h + (i>>4)][4*(i&15) + 0..3]  (one float4)
    float4 buf0[PF], buf1[PF];
    const size_t laneoff = (size_t)((w << 9) + (lane << 2));   // float offset

#pragma unroll
    for (int p = 0; p < PF; ++p) {
        const float4* gp = (const float4*)(G_weight + (((size_t)ids[p]) << 12) + laneoff);
        buf0[p] = gp[0];    // chunk0 (256 floats below)
        buf1[p] = gp[64];   // chunk1 (+256 floats)
    }

#pragma unroll 1
    for (int t0 = 0; t0 < SEQ; t0 += PF) {
#pragma unroll
        for (int u = 0; u < PF; ++u) {
            const int t  = t0 + u;
            const int pb = t & 1;

            // v[k] for this lane's two rows (index uniform per 16-lane group -> bpermute)
            const float va = __shfl(vj, (w << 3) + rq,     64);
            const float vb = __shfl(vj, (w << 3) + rq + 4, 64);

            const float4 m0 = buf0[u];
            const float4 m1 = buf1[u];

            // issue prefetch for step t+PF into the freed slot (static index u)
            {
                int nx = t + PF; nx = (nx < SEQ) ? nx : (SEQ - 1);
                const float4* gp = (const float4*)(G_weight + (((size_t)ids[nx]) << 12) + laneoff);
                buf0[u] = gp[0];
                buf1[u] = gp[64];
            }

            // partial products for this lane's 4 columns
            float fx = fmaf(va, m0.x, vb * m1.x);
            float fy = fmaf(va, m0.y, vb * m1.y);
            float fz = fmaf(va, m0.z, vb * m1.z);
            float fw = fmaf(va, m0.w, vb * m1.w);

            // reduce the 4 stride-16 lanes holding the same columns (rows 8w..8w+3 / +4)
            fx += __shfl_xor(fx, 16, 64); fy += __shfl_xor(fy, 16, 64);
            fz += __shfl_xor(fz, 16, 64); fw += __shfl_xor(fw, 16, 64);
            fx += __shfl_xor(fx, 32, 64); fy += __shfl_xor(fy, 32, 64);
            fz += __shfl_xor(fz, 32, 64); fw += __shfl_xor(fw, 32, 64);

            // one replicate (lanes 0..15) publishes the wave's 64 column-sums
            if (rq == 0) {
                *(float4*)&partial[pb][(w << 6) + (lane << 2)] =
                    make_float4(fx, fy, fz, fw);
            }

            // raw barrier: drain LDS ops only — global prefetches stay in flight
            asm volatile("s_waitcnt lgkmcnt(0)\n\ts_barrier" ::: "memory");

            // cross-wave reduce: lane j sums column j over the 8 waves
            float nv = 0.f;
#pragma unroll
            for (int q = 0; q < NW; ++q)
                nv += partial[pb][(q << 6) + lane];
            vj = nv;
            // no second barrier: next step writes partial[pb^1]; the step-after-next
            // write to partial[pb] is ordered behind every wave's reads by the barrier
        }
    }

    // epilogue on wave 0: normalize + (2 x 64) linear
    if (w == 0) {
        float s = vj * vj;
#pragma unroll
        for (int off = 32; off >= 1; off >>= 1)
            s += __shfl_xor(s, off, 64);
        const float inv = 1.0f / fmaxf(sqrtf(s), 1e-12f);
        const float nj  = vj * inv;

        float d0 = nj * lin_W[lane];
        float d1 = nj * lin_W[RDIM + lane];
#pragma unroll
        for (int off = 32; off >= 1; off >>= 1) {
            d0 += __shfl_xor(d0, off, 64);
            d1 += __shfl_xor(d1, off, 64);
        }
        if (lane == 0) {
            out[b * 2 + 0] = d0 + lin_b[0];
            out[b * 2 + 1] = d1 + lin_b[1];
        }
    }
}

extern "C" void kernel_launch(void* const* d_in, const int* in_sizes, int n_in,
                              void* d_out, int out_size, void* d_ws, size_t ws_size,
                              hipStream_t stream) {
    const int*   input_ids = (const int*)d_in[0];
    // d_in[1] = mask, d_in[2] = segment_ids, d_in[3] = seq_lengths — unused
    const float* G_weight  = (const float*)d_in[4];
    const float* G1_weight = (const float*)d_in[5];
    const float* lin_W     = (const float*)d_in[6];
    const float* lin_b     = (const float*)d_in[7];
    float*       out       = (float*)d_out;

    matchain_kernel<<<64, 512, 0, stream>>>(input_ids, G_weight, G1_weight, lin_W, lin_b, out);
}

// Round 3
// 179.649 us; speedup vs baseline: 2.1467x; 1.2317x over previous
//
#include <hip/hip_runtime.h>
#include <math.h>

#define SEQ   512
#define RDIM  64
#define NW    4     // waves per block
#define KPW   16    // k-rows per wave

__global__ __launch_bounds__(256, 1)
void matchain_kernel(const int* __restrict__ input_ids,
                     const float* __restrict__ G_weight,
                     const float* __restrict__ G1_weight,
                     const float* __restrict__ lin_W,
                     const float* __restrict__ lin_b,
                     float* __restrict__ out)
{
    __shared__ int   ids[SEQ];
    __shared__ float part[2][NW][RDIM];

    const int tid  = threadIdx.x;
    const int lane = tid & 63;
    const int w    = tid >> 6;         // wave 0..3
    const int b    = blockIdx.x;

    ids[tid]       = input_ids[b * SEQ + tid];
    ids[tid + 256] = input_ids[b * SEQ + tid + 256];
    __syncthreads();

    // wave-uniform k-row base (16w) as SGPR
    const int wbase = __builtin_amdgcn_readfirstlane(w << 4);

    // v: lane j holds v[j]; per-wave k-slice lives in SGPRs sv[0..15]
    float vj = G1_weight[lane];
    float sv[KPW];
#pragma unroll
    for (int i = 0; i < KPW; ++i)
        sv[i] = __int_as_float(__builtin_amdgcn_readlane(__float_as_int(vj), wbase + i));

    // column registers: c[i] = M[16w+i][lane]; 4 buffers = prefetch depth 4
    float c0[KPW], c1[KPW], c2[KPW], c3[KPW];

    // issue 16 coalesced row-loads of matrix `id_` into buffer C
#define ISSUE(C, id_) do {                                                        \
        const float* p_ = G_weight + ((size_t)(id_) << 12) + (wbase << 6) + lane; \
        _Pragma("unroll")                                                         \
        for (int i = 0; i < KPW; ++i) C[i] = p_[i * RDIM];                        \
    } while (0)

    // prologue: prime buffers for steps 0..3
    ISSUE(c0, __builtin_amdgcn_readfirstlane(ids[0]));
    ISSUE(c1, __builtin_amdgcn_readfirstlane(ids[1]));
    ISSUE(c2, __builtin_amdgcn_readfirstlane(ids[2]));
    ISSUE(c3, __builtin_amdgcn_readfirstlane(ids[3]));

    int pend = ids[4];   // id for the next prefetch, read one body ahead

#define BODY(C, T) do {                                                           \
        /* partial over this wave's 16 k-rows (SGPR x VGPR fmac) */               \
        float a0_ = sv[0] * C[0];                                                 \
        float a1_ = sv[1] * C[1];                                                 \
        _Pragma("unroll")                                                         \
        for (int i = 2; i < KPW; i += 2) {                                        \
            a0_ = fmaf(sv[i],     C[i],     a0_);                                 \
            a1_ = fmaf(sv[i + 1], C[i + 1], a1_);                                 \
        }                                                                         \
        /* prefetch step T+4 into the just-freed buffer (id read last body) */    \
        {                                                                         \
            const int idn_ = __builtin_amdgcn_readfirstlane(pend);                \
            ISSUE(C, idn_);                                                       \
            const int nx_ = ((T) + 5 < SEQ) ? ((T) + 5) : (SEQ - 1);              \
            pend = ids[nx_];                                                      \
        }                                                                         \
        const int pb_ = (T) & 1;                                                  \
        part[pb_][w][lane] = a0_ + a1_;                                           \
        /* drain LDS only; global prefetches stay in flight across the barrier */ \
        asm volatile("s_waitcnt lgkmcnt(0)\n\ts_barrier" ::: "memory");           \
        vj = (part[pb_][0][lane] + part[pb_][1][lane])                            \
           + (part[pb_][2][lane] + part[pb_][3][lane]);                           \
        _Pragma("unroll")                                                         \
        for (int i = 0; i < KPW; ++i)                                             \
            sv[i] = __int_as_float(                                               \
                __builtin_amdgcn_readlane(__float_as_int(vj), wbase + i));        \
    } while (0)

#pragma unroll 1
    for (int t0 = 0; t0 < SEQ; t0 += 4) {
        BODY(c0, t0 + 0);
        BODY(c1, t0 + 1);
        BODY(c2, t0 + 2);
        BODY(c3, t0 + 3);
    }

    // epilogue on wave 0: normalize + (2 x 64) linear
    if (w == 0) {
        float s = vj * vj;
#pragma unroll
        for (int off = 32; off >= 1; off >>= 1)
            s += __shfl_xor(s, off, 64);
        const float inv = 1.0f / fmaxf(sqrtf(s), 1e-12f);
        const float nj  = vj * inv;

        float d0 = nj * lin_W[lane];
        float d1 = nj * lin_W[RDIM + lane];
#pragma unroll
        for (int off = 32; off >= 1; off >>= 1) {
            d0 += __shfl_xor(d0, off, 64);
            d1 += __shfl_xor(d1, off, 64);
        }
        if (lane == 0) {
            out[b * 2 + 0] = d0 + lin_b[0];
            out[b * 2 + 1] = d1 + lin_b[1];
        }
    }
}

extern "C" void kernel_launch(void* const* d_in, const int* in_sizes, int n_in,
                              void* d_out, int out_size, void* d_ws, size_t ws_size,
                              hipStream_t stream) {
    const int*   input_ids = (const int*)d_in[0];
    // d_in[1] = mask, d_in[2] = segment_ids, d_in[3] = seq_lengths — unused
    const float* G_weight  = (const float*)d_in[4];
    const float* G1_weight = (const float*)d_in[5];
    const float* lin_W     = (const float*)d_in[6];
    const float* lin_b     = (const float*)d_in[7];
    float*       out       = (float*)d_out;

    matchain_kernel<<<64, 256, 0, stream>>>(input_ids, G_weight, G1_weight, lin_W, lin_b, out);
}

// Round 5
// 164.148 us; speedup vs baseline: 2.3494x; 1.0944x over previous
//
#include <hip/hip_runtime.h>
#include <math.h>

#define SEQ   512
#define RDIM  64
#define NW    8      // waves per block (512 threads)
#define DPTH  16     // prefetch depth in steps (2 x4-loads/step -> 32 outstanding)
#define STRD  12     // floats per part row: 8 used + 4 pad (keeps b128 alignment)

typedef unsigned int u32x2 __attribute__((ext_vector_type(2)));

// butterfly sum across the four 16-lane subgroups: every lane gets
// sum over lanes {p16, p16+16, p16+32, p16+48}
__device__ __forceinline__ float qreduce4(float x) {
#if __has_builtin(__builtin_amdgcn_permlane16_swap) && __has_builtin(__builtin_amdgcn_permlane32_swap)
    u32x2 a = __builtin_amdgcn_permlane16_swap(__float_as_uint(x), __float_as_uint(x), false, false);
    const float y = __uint_as_float(a.x) + __uint_as_float(a.y);
    u32x2 c = __builtin_amdgcn_permlane32_swap(__float_as_uint(y), __float_as_uint(y), false, false);
    return __uint_as_float(c.x) + __uint_as_float(c.y);
#else
    x += __shfl_xor(x, 16, 64);
    x += __shfl_xor(x, 32, 64);
    return x;
#endif
}

__global__ __launch_bounds__(512, 2)
void matchain_kernel(const int* __restrict__ input_ids,
                     const float* __restrict__ G_weight,
                     const float* __restrict__ G1_weight,
                     const float* __restrict__ lin_W,
                     const float* __restrict__ lin_b,
                     float* __restrict__ out)
{
    __shared__ int   ids[SEQ];
    __shared__ __align__(16) float part[2][RDIM][STRD];

    const int tid  = threadIdx.x;
    const int lane = tid & 63;
    const int w    = tid >> 6;       // wave 0..7
    const int b    = blockIdx.x;
    const int sub  = lane >> 4;      // 0..3 : row-subgroup within the x4 load
    const int p16  = lane & 15;      // column group: this lane owns cols 4*p16..4*p16+3

    ids[tid] = input_ids[b * SEQ + tid];
    __syncthreads();

    // wave w owns rows [8w, 8w+8): m=0 -> row 8w+sub, m=1 -> row 8w+4+sub
    const int k0 = (w << 3) + sub;

    // v multipliers for this lane's two rows (init from G1)
    float vm0 = G1_weight[k0];
    float vm1 = G1_weight[k0 + 4];

    // per-lane float offsets inside a 64x64 matrix for the two 1KB loads
    const size_t lo0 = (size_t)((w << 9) + (sub << 6) + (p16 << 2)); // m=0
    const size_t lo1 = lo0 + 256;                                    // m=1 (+1024B)

    float4 bufA[DPTH], bufB[DPTH];

#define ISSUE(S, id_) do {                                        \
        const float* bp_ = G_weight + (((size_t)(id_)) << 12);    \
        bufA[S] = *(const float4*)(bp_ + lo0);                    \
        bufB[S] = *(const float4*)(bp_ + lo1);                    \
    } while (0)

    // prologue: prime slots 0..DPTH-1 for steps 0..DPTH-1
#pragma unroll
    for (int p = 0; p < DPTH; ++p)
        ISSUE(p, __builtin_amdgcn_readfirstlane(ids[p]));

    int pend = ids[DPTH];

#define BODY(S, K) do {                                                        \
        const float4 a_ = bufA[S];                                             \
        const float4 c_ = bufB[S];                                             \
        float fx = fmaf(vm0, a_.x, vm1 * c_.x);                                \
        float fy = fmaf(vm0, a_.y, vm1 * c_.y);                                \
        float fz = fmaf(vm0, a_.z, vm1 * c_.z);                                \
        float fw = fmaf(vm0, a_.w, vm1 * c_.w);                                \
        /* prefetch step t0+K+DPTH into the just-consumed slot */              \
        {                                                                      \
            const int idn_ = __builtin_amdgcn_readfirstlane(pend);             \
            ISSUE(S, idn_);                                                    \
            int nx_ = t0 + (K) + DPTH + 1;                                     \
            nx_ = (nx_ < SEQ) ? nx_ : (SEQ - 1);                               \
            pend = ids[nx_];                                                   \
        }                                                                      \
        fx = qreduce4(fx); fy = qreduce4(fy);                                  \
        fz = qreduce4(fz); fw = qreduce4(fw);                                  \
        /* 4 lanes per p16 group hold identical sums; lane sub picks col */    \
        const float wv_ = (sub == 0) ? fx : (sub == 1) ? fy                    \
                        : (sub == 2) ? fz : fw;                                \
        part[(K) & 1][(p16 << 2) + sub][w] = wv_;                              \
        asm volatile("s_waitcnt lgkmcnt(0)\n\ts_barrier" ::: "memory");        \
        /* rebuild v for the next step: sum 8 wave-partials per row index */   \
        {                                                                      \
            const float4* pk0_ = (const float4*)&part[(K) & 1][k0][0];         \
            const float4  r0_  = pk0_[0], r1_ = pk0_[1];                       \
            vm0 = ((r0_.x + r0_.y) + (r0_.z + r0_.w))                          \
                + ((r1_.x + r1_.y) + (r1_.z + r1_.w));                         \
            const float4* pk1_ = (const float4*)&part[(K) & 1][k0 + 4][0];     \
            const float4  s0_  = pk1_[0], s1_ = pk1_[1];                       \
            vm1 = ((s0_.x + s0_.y) + (s0_.z + s0_.w))                          \
                + ((s1_.x + s1_.y) + (s1_.z + s1_.w));                         \
        }                                                                      \
    } while (0)

#pragma unroll 1
    for (int t0 = 0; t0 < SEQ; t0 += DPTH) {
        BODY( 0,  0); BODY( 1,  1); BODY( 2,  2); BODY( 3,  3);
        BODY( 4,  4); BODY( 5,  5); BODY( 6,  6); BODY( 7,  7);
        BODY( 8,  8); BODY( 9,  9); BODY(10, 10); BODY(11, 11);
        BODY(12, 12); BODY(13, 13); BODY(14, 14); BODY(15, 15);
    }

    // drain leftover (never-consumed) tail prefetches
    asm volatile("s_waitcnt vmcnt(0)" ::: "memory");

    // final v: lane j sums the 8 wave-partials of column j (step 511 -> pb=1)
    float vj;
    {
        const float4* pj = (const float4*)&part[1][lane][0];
        const float4 q0 = pj[0], q1 = pj[1];
        vj = ((q0.x + q0.y) + (q0.z + q0.w)) + ((q1.x + q1.y) + (q1.z + q1.w));
    }

    // epilogue on wave 0: normalize + (2 x 64) linear
    if (w == 0) {
        float s = vj * vj;
#pragma unroll
        for (int off = 32; off >= 1; off >>= 1)
            s += __shfl_xor(s, off, 64);
        const float inv = 1.0f / fmaxf(sqrtf(s), 1e-12f);
        const float nj  = vj * inv;

        float d0 = nj * lin_W[lane];
        float d1 = nj * lin_W[RDIM + lane];
#pragma unroll
        for (int off = 32; off >= 1; off >>= 1) {
            d0 += __shfl_xor(d0, off, 64);
            d1 += __shfl_xor(d1, off, 64);
        }
        if (lane == 0) {
            out[b * 2 + 0] = d0 + lin_b[0];
            out[b * 2 + 1] = d1 + lin_b[1];
        }
    }
}

extern "C" void kernel_launch(void* const* d_in, const int* in_sizes, int n_in,
                              void* d_out, int out_size, void* d_ws, size_t ws_size,
                              hipStream_t stream) {
    const int*   input_ids = (const int*)d_in[0];
    // d_in[1] = mask, d_in[2] = segment_ids, d_in[3] = seq_lengths — unused
    const float* G_weight  = (const float*)d_in[4];
    const float* G1_weight = (const float*)d_in[5];
    const float* lin_W     = (const float*)d_in[6];
    const float* lin_b     = (const float*)d_in[7];
    float*       out       = (float*)d_out;

    matchain_kernel<<<64, 512, 0, stream>>>(input_ids, G_weight, G1_weight, lin_W, lin_b, out);
}

// Round 6
// 121.334 us; speedup vs baseline: 3.1784x; 1.3529x over previous
//
#include <hip/hip_runtime.h>
#include <math.h>

#define SEQ   512
#define RDIM  64
#define NB    64
#define SEGL  16
#define SEGS  32   // SEQ/SEGL

typedef short  v4s __attribute__((ext_vector_type(4)));
typedef float  v4f __attribute__((ext_vector_type(4)));
typedef short  s8v __attribute__((ext_vector_type(8)));
typedef unsigned int u32x2 __attribute__((ext_vector_type(2)));

__device__ __forceinline__ v4f mfma16(v4s a, v4s b, v4f c) {
#if __has_builtin(__builtin_amdgcn_mfma_f32_16x16x16bf16_1k)
    return __builtin_amdgcn_mfma_f32_16x16x16bf16_1k(a, b, c, 0, 0, 0);
#else
    v4f d;
    asm volatile("v_mfma_f32_16x16x16_bf16 %0, %1, %2, %3"
                 : "=v"(d) : "v"(a), "v"(b), "v"(c));
    return d;
#endif
}

__device__ __forceinline__ unsigned short bf16_rne(float x) {
    unsigned int u = __float_as_uint(x);
    unsigned int r = u + 0x7FFFu + ((u >> 16) & 1u);
    return (unsigned short)(r >> 16);
}
__device__ __forceinline__ float bf16_tof(unsigned short h) {
    return __uint_as_float(((unsigned int)h) << 16);
}

// ---------------- Phase 1: segment products via split-bf16 MFMA ----------------
// Block (b,s): Q = M_{16s} * M_{16s+1} * ... * M_{16s+15}, built descending:
// Q <- M_t * Q. Q carried in C-regs; C-layout == B-frag layout (in-lane identity).
__global__ __launch_bounds__(256, 3)
void seg_kernel(const int* __restrict__ input_ids,
                const float* __restrict__ G_weight,
                float* __restrict__ ws)
{
    __shared__ s8v bexch[2][16][64];   // [pb][kc*4+jb][lane] = {Qh[0..3], Ql[0..3]}

    const int tid = threadIdx.x;
    const int l   = tid & 63;
    const int w   = tid >> 6;     // wave 0..3 = A-row block / D-row block
    const int g   = l >> 4;
    const int rl  = l & 15;
    const int blk = blockIdx.x;
    const int b   = blk >> 5;
    const int s   = blk & 31;

    // matrices consumed: init = t0+15, step i (1..15) uses t0+15-i
    int mseq[16];
#pragma unroll
    for (int i = 0; i < 16; ++i)
        mseq[i] = input_ids[(b << 9) + (s << 4) + (15 - i)];

    // acc tile (w,jb): element (16w + 4g + r, 16jb + rl). Init Q = M_last.
    v4f acc[4];
    {
        const float* p0 = G_weight + (((size_t)__builtin_amdgcn_readfirstlane(mseq[0])) << 12);
#pragma unroll
        for (int jb = 0; jb < 4; ++jb)
#pragma unroll
            for (int r = 0; r < 4; ++r)
                acc[jb][r] = p0[(((w << 4) + (g << 2) + r) << 6) + (jb << 4) + rl];
    }

    // A-operand rows of M: lane l holds row 16w+rl, cols 16kc+4g..+3 (one float4/kc)
    const size_t aoff = (size_t)((((w << 4) + rl) << 6) + (g << 2));
    float4 pA0[4], pA1[4], pA2[4], pA3[4];

#define ISSUEA(P, IDX) do {                                                \
        const float* gp_ = G_weight + (((size_t)(IDX)) << 12) + aoff;      \
        P[0] = *(const float4*)(gp_);                                      \
        P[1] = *(const float4*)(gp_ + 16);                                 \
        P[2] = *(const float4*)(gp_ + 32);                                 \
        P[3] = *(const float4*)(gp_ + 48);                                 \
    } while (0)

    ISSUEA(pA0, __builtin_amdgcn_readfirstlane(mseq[1]));
    ISSUEA(pA1, __builtin_amdgcn_readfirstlane(mseq[2]));
    ISSUEA(pA2, __builtin_amdgcn_readfirstlane(mseq[3]));
    ISSUEA(pA3, __builtin_amdgcn_readfirstlane(mseq[4]));

#define SBODY(P, I) do {                                                        \
        const int pb_ = (I) & 1;                                                \
        /* publish Q (=acc) as split B-frags */                                 \
        _Pragma("unroll")                                                       \
        for (int jb = 0; jb < 4; ++jb) {                                        \
            s8v pk;                                                             \
            _Pragma("unroll")                                                   \
            for (int r = 0; r < 4; ++r) {                                       \
                const unsigned short h_ = bf16_rne(acc[jb][r]);                 \
                pk[r]     = (short)h_;                                          \
                pk[4 + r] = (short)bf16_rne(acc[jb][r] - bf16_tof(h_));         \
            }                                                                   \
            bexch[pb_][(w << 2) + jb][l] = pk;                                  \
        }                                                                       \
        /* split prefetched A rows */                                           \
        v4s Ah[4], Al[4];                                                       \
        _Pragma("unroll")                                                       \
        for (int kc = 0; kc < 4; ++kc) {                                        \
            const float e_[4] = {P[kc].x, P[kc].y, P[kc].z, P[kc].w};           \
            _Pragma("unroll")                                                   \
            for (int j = 0; j < 4; ++j) {                                       \
                const unsigned short h_ = bf16_rne(e_[j]);                      \
                Ah[kc][j] = (short)h_;                                          \
                Al[kc][j] = (short)bf16_rne(e_[j] - bf16_tof(h_));              \
            }                                                                   \
        }                                                                       \
        if ((I) + 4 <= 15)                                                      \
            ISSUEA(P, __builtin_amdgcn_readfirstlane(mseq[(I) + 4]));           \
        asm volatile("s_waitcnt lgkmcnt(0)\n\ts_barrier" ::: "memory");         \
        v4f na[4] = {{0,0,0,0},{0,0,0,0},{0,0,0,0},{0,0,0,0}};                  \
        _Pragma("unroll")                                                       \
        for (int kc = 0; kc < 4; ++kc) {                                        \
            _Pragma("unroll")                                                   \
            for (int jb = 0; jb < 4; ++jb) {                                    \
                const s8v q_ = bexch[pb_][(kc << 2) + jb][l];                   \
                const v4s qh = {q_[0], q_[1], q_[2], q_[3]};                    \
                const v4s ql = {q_[4], q_[5], q_[6], q_[7]};                    \
                na[jb] = mfma16(Ah[kc], qh, na[jb]);                            \
                na[jb] = mfma16(Al[kc], qh, na[jb]);                            \
                na[jb] = mfma16(Ah[kc], ql, na[jb]);                            \
            }                                                                   \
        }                                                                       \
        _Pragma("unroll")                                                       \
        for (int jb = 0; jb < 4; ++jb) acc[jb] = na[jb];                        \
    } while (0)

    SBODY(pA0,  1); SBODY(pA1,  2); SBODY(pA2,  3); SBODY(pA3,  4);
    SBODY(pA0,  5); SBODY(pA1,  6); SBODY(pA2,  7); SBODY(pA3,  8);
    SBODY(pA0,  9); SBODY(pA1, 10); SBODY(pA2, 11); SBODY(pA3, 12);
    SBODY(pA0, 13); SBODY(pA1, 14); SBODY(pA2, 15);

    float* wp = ws + (((size_t)blk) << 12);
#pragma unroll
    for (int jb = 0; jb < 4; ++jb)
#pragma unroll
        for (int r = 0; r < 4; ++r)
            wp[(((w << 4) + (g << 2) + r) << 6) + (jb << 4) + rl] = acc[jb][r];
}

// ---------------- Phase 2: 32-step vector chain over segment products ----------------
__device__ __forceinline__ float qreduce4(float x) {
#if __has_builtin(__builtin_amdgcn_permlane16_swap) && __has_builtin(__builtin_amdgcn_permlane32_swap)
    u32x2 a = __builtin_amdgcn_permlane16_swap(__float_as_uint(x), __float_as_uint(x), false, false);
    const float y = __uint_as_float(a.x) + __uint_as_float(a.y);
    u32x2 c = __builtin_amdgcn_permlane32_swap(__float_as_uint(y), __float_as_uint(y), false, false);
    return __uint_as_float(c.x) + __uint_as_float(c.y);
#else
    x += __shfl_xor(x, 16, 64);
    x += __shfl_xor(x, 32, 64);
    return x;
#endif
}

#define STRD 12

__global__ __launch_bounds__(512, 2)
void chain2_kernel(const float* __restrict__ ws,
                   const float* __restrict__ G1_weight,
                   const float* __restrict__ lin_W,
                   const float* __restrict__ lin_b,
                   float* __restrict__ out)
{
    __shared__ __align__(16) float part[2][RDIM][STRD];

    const int tid  = threadIdx.x;
    const int lane = tid & 63;
    const int w    = tid >> 6;
    const int b    = blockIdx.x;
    const int sub  = lane >> 4;
    const int p16  = lane & 15;

    const int k0 = (w << 3) + sub;
    float vm0 = G1_weight[k0];
    float vm1 = G1_weight[k0 + 4];

    const size_t lo0 = (size_t)((w << 9) + (sub << 6) + (p16 << 2));
    const size_t lo1 = lo0 + 256;

    float4 bufA[16], bufB[16];

#define ISSUE2(S, T) do {                                                  \
        const float* bp_ = ws + (((size_t)((b << 5) + (T))) << 12);        \
        bufA[S] = *(const float4*)(bp_ + lo0);                             \
        bufB[S] = *(const float4*)(bp_ + lo1);                             \
    } while (0)

#pragma unroll
    for (int p = 0; p < 16; ++p) ISSUE2(p, p);

#define BODY2(S, T) do {                                                       \
        const float4 a_ = bufA[S];                                             \
        const float4 c_ = bufB[S];                                             \
        float fx = fmaf(vm0, a_.x, vm1 * c_.x);                                \
        float fy = fmaf(vm0, a_.y, vm1 * c_.y);                                \
        float fz = fmaf(vm0, a_.z, vm1 * c_.z);                                \
        float fw = fmaf(vm0, a_.w, vm1 * c_.w);                                \
        { int nx_ = (T) + 16; nx_ = (nx_ < SEGS) ? nx_ : (SEGS - 1);           \
          ISSUE2(S, nx_); }                                                    \
        fx = qreduce4(fx); fy = qreduce4(fy);                                  \
        fz = qreduce4(fz); fw = qreduce4(fw);                                  \
        const float wv_ = (sub == 0) ? fx : (sub == 1) ? fy                    \
                        : (sub == 2) ? fz : fw;                                \
        part[(T) & 1][(p16 << 2) + sub][w] = wv_;                              \
        asm volatile("s_waitcnt lgkmcnt(0)\n\ts_barrier" ::: "memory");        \
        {                                                                      \
            const float4* pk0_ = (const float4*)&part[(T) & 1][k0][0];         \
            const float4  r0_  = pk0_[0], r1_ = pk0_[1];                       \
            vm0 = ((r0_.x + r0_.y) + (r0_.z + r0_.w))                          \
                + ((r1_.x + r1_.y) + (r1_.z + r1_.w));                         \
            const float4* pk1_ = (const float4*)&part[(T) & 1][k0 + 4][0];     \
            const float4  s0_  = pk1_[0], s1_ = pk1_[1];                       \
            vm1 = ((s0_.x + s0_.y) + (s0_.z + s0_.w))                          \
                + ((s1_.x + s1_.y) + (s1_.z + s1_.w));                         \
        }                                                                      \
    } while (0)

    BODY2( 0,  0); BODY2( 1,  1); BODY2( 2,  2); BODY2( 3,  3);
    BODY2( 4,  4); BODY2( 5,  5); BODY2( 6,  6); BODY2( 7,  7);
    BODY2( 8,  8); BODY2( 9,  9); BODY2(10, 10); BODY2(11, 11);
    BODY2(12, 12); BODY2(13, 13); BODY2(14, 14); BODY2(15, 15);
    BODY2( 0, 16); BODY2( 1, 17); BODY2( 2, 18); BODY2( 3, 19);
    BODY2( 4, 20); BODY2( 5, 21); BODY2( 6, 22); BODY2( 7, 23);
    BODY2( 8, 24); BODY2( 9, 25); BODY2(10, 26); BODY2(11, 27);
    BODY2(12, 28); BODY2(13, 29); BODY2(14, 30); BODY2(15, 31);

    asm volatile("s_waitcnt vmcnt(0)" ::: "memory");

    float vj;
    {
        const float4* pj = (const float4*)&part[1][lane][0];
        const float4 q0 = pj[0], q1 = pj[1];
        vj = ((q0.x + q0.y) + (q0.z + q0.w)) + ((q1.x + q1.y) + (q1.z + q1.w));
    }

    if (w == 0) {
        float ss = vj * vj;
#pragma unroll
        for (int off = 32; off >= 1; off >>= 1)
            ss += __shfl_xor(ss, off, 64);
        const float inv = 1.0f / fmaxf(sqrtf(ss), 1e-12f);
        const float nj  = vj * inv;

        float d0 = nj * lin_W[lane];
        float d1 = nj * lin_W[RDIM + lane];
#pragma unroll
        for (int off = 32; off >= 1; off >>= 1) {
            d0 += __shfl_xor(d0, off, 64);
            d1 += __shfl_xor(d1, off, 64);
        }
        if (lane == 0) {
            out[b * 2 + 0] = d0 + lin_b[0];
            out[b * 2 + 1] = d1 + lin_b[1];
        }
    }
}

// ---------------- Fallback: proven round-5 single-kernel chain ----------------
__global__ __launch_bounds__(512, 2)
void matchain_kernel(const int* __restrict__ input_ids,
                     const float* __restrict__ G_weight,
                     const float* __restrict__ G1_weight,
                     const float* __restrict__ lin_W,
                     const float* __restrict__ lin_b,
                     float* __restrict__ out)
{
    __shared__ int   ids[SEQ];
    __shared__ __align__(16) float part[2][RDIM][STRD];

    const int tid  = threadIdx.x;
    const int lane = tid & 63;
    const int w    = tid >> 6;
    const int b    = blockIdx.x;
    const int sub  = lane >> 4;
    const int p16  = lane & 15;

    ids[tid] = input_ids[b * SEQ + tid];
    __syncthreads();

    const int k0 = (w << 3) + sub;
    float vm0 = G1_weight[k0];
    float vm1 = G1_weight[k0 + 4];

    const size_t lo0 = (size_t)((w << 9) + (sub << 6) + (p16 << 2));
    const size_t lo1 = lo0 + 256;

    float4 bufA[16], bufB[16];

#define ISSUE(S, id_) do {                                        \
        const float* bp_ = G_weight + (((size_t)(id_)) << 12);    \
        bufA[S] = *(const float4*)(bp_ + lo0);                    \
        bufB[S] = *(const float4*)(bp_ + lo1);                    \
    } while (0)

#pragma unroll
    for (int p = 0; p < 16; ++p)
        ISSUE(p, __builtin_amdgcn_readfirstlane(ids[p]));

    int pend = ids[16];

#define BODY(S, K) do {                                                        \
        const float4 a_ = bufA[S];                                             \
        const float4 c_ = bufB[S];                                             \
        float fx = fmaf(vm0, a_.x, vm1 * c_.x);                                \
        float fy = fmaf(vm0, a_.y, vm1 * c_.y);                                \
        float fz = fmaf(vm0, a_.z, vm1 * c_.z);                                \
        float fw = fmaf(vm0, a_.w, vm1 * c_.w);                                \
        {                                                                      \
            const int idn_ = __builtin_amdgcn_readfirstlane(pend);             \
            ISSUE(S, idn_);                                                    \
            int nx_ = t0 + (K) + 17;                                           \
            nx_ = (nx_ < SEQ) ? nx_ : (SEQ - 1);                               \
            pend = ids[nx_];                                                   \
        }                                                                      \
        fx = qreduce4(fx); fy = qreduce4(fy);                                  \
        fz = qreduce4(fz); fw = qreduce4(fw);                                  \
        const float wv_ = (sub == 0) ? fx : (sub == 1) ? fy                    \
                        : (sub == 2) ? fz : fw;                                \
        part[(K) & 1][(p16 << 2) + sub][w] = wv_;                              \
        asm volatile("s_waitcnt lgkmcnt(0)\n\ts_barrier" ::: "memory");        \
        {                                                                      \
            const float4* pk0_ = (const float4*)&part[(K) & 1][k0][0];         \
            const float4  r0_  = pk0_[0], r1_ = pk0_[1];                       \
            vm0 = ((r0_.x + r0_.y) + (r0_.z + r0_.w))                          \
                + ((r1_.x + r1_.y) + (r1_.z + r1_.w));                         \
            const float4* pk1_ = (const float4*)&part[(K) & 1][k0 + 4][0];     \
            const float4  s0_  = pk1_[0], s1_ = pk1_[1];                       \
            vm1 = ((s0_.x + s0_.y) + (s0_.z + s0_.w))                          \
                + ((s1_.x + s1_.y) + (s1_.z + s1_.w));                         \
        }                                                                      \
    } while (0)

#pragma unroll 1
    for (int t0 = 0; t0 < SEQ; t0 += 16) {
        BODY( 0,  0); BODY( 1,  1); BODY( 2,  2); BODY( 3,  3);
        BODY( 4,  4); BODY( 5,  5); BODY( 6,  6); BODY( 7,  7);
        BODY( 8,  8); BODY( 9,  9); BODY(10, 10); BODY(11, 11);
        BODY(12, 12); BODY(13, 13); BODY(14, 14); BODY(15, 15);
    }

    asm volatile("s_waitcnt vmcnt(0)" ::: "memory");

    float vj;
    {
        const float4* pj = (const float4*)&part[1][lane][0];
        const float4 q0 = pj[0], q1 = pj[1];
        vj = ((q0.x + q0.y) + (q0.z + q0.w)) + ((q1.x + q1.y) + (q1.z + q1.w));
    }

    if (w == 0) {
        float ss = vj * vj;
#pragma unroll
        for (int off = 32; off >= 1; off >>= 1)
            ss += __shfl_xor(ss, off, 64);
        const float inv = 1.0f / fmaxf(sqrtf(ss), 1e-12f);
        const float nj  = vj * inv;

        float d0 = nj * lin_W[lane];
        float d1 = nj * lin_W[RDIM + lane];
#pragma unroll
        for (int off = 32; off >= 1; off >>= 1) {
            d0 += __shfl_xor(d0, off, 64);
            d1 += __shfl_xor(d1, off, 64);
        }
        if (lane == 0) {
            out[b * 2 + 0] = d0 + lin_b[0];
            out[b * 2 + 1] = d1 + lin_b[1];
        }
    }
}

extern "C" void kernel_launch(void* const* d_in, const int* in_sizes, int n_in,
                              void* d_out, int out_size, void* d_ws, size_t ws_size,
                              hipStream_t stream) {
    const int*   input_ids = (const int*)d_in[0];
    // d_in[1] = mask, d_in[2] = segment_ids, d_in[3] = seq_lengths — unused
    const float* G_weight  = (const float*)d_in[4];
    const float* G1_weight = (const float*)d_in[5];
    const float* lin_W     = (const float*)d_in[6];
    const float* lin_b     = (const float*)d_in[7];
    float*       out       = (float*)d_out;

    const size_t need = (size_t)NB * SEGS * RDIM * RDIM * sizeof(float); // 32 MB
    if (ws_size >= need) {
        float* ws = (float*)d_ws;
        seg_kernel<<<NB * SEGS, 256, 0, stream>>>(input_ids, G_weight, ws);
        chain2_kernel<<<NB, 512, 0, stream>>>(ws, G1_weight, lin_W, lin_b, out);
    } else {
        matchain_kernel<<<NB, 512, 0, stream>>>(input_ids, G_weight, G1_weight,
                                                lin_W, lin_b, out);
    }
}

// Round 7
// 120.360 us; speedup vs baseline: 3.2041x; 1.0081x over previous
//
#include <hip/hip_runtime.h>
#include <math.h>

#define SEQ   512
#define RDIM  64
#define NB    64
#define SEGL  16
#define SEGS  32   // SEQ/SEGL

typedef short  v4s __attribute__((ext_vector_type(4)));
typedef float  v4f __attribute__((ext_vector_type(4)));
typedef short  s8v __attribute__((ext_vector_type(8)));
typedef unsigned int u32x2 __attribute__((ext_vector_type(2)));

__device__ __forceinline__ v4f mfma16(v4s a, v4s b, v4f c) {
#if __has_builtin(__builtin_amdgcn_mfma_f32_16x16x16bf16_1k)
    return __builtin_amdgcn_mfma_f32_16x16x16bf16_1k(a, b, c, 0, 0, 0);
#else
    v4f d;
    asm volatile("v_mfma_f32_16x16x16_bf16 %0, %1, %2, %3"
                 : "=v"(d) : "v"(a), "v"(b), "v"(c));
    return d;
#endif
}

__device__ __forceinline__ unsigned short bf16_rne(float x) {
    unsigned int u = __float_as_uint(x);
    unsigned int r = u + 0x7FFFu + ((u >> 16) & 1u);
    return (unsigned short)(r >> 16);
}
__device__ __forceinline__ float bf16_tof(unsigned short h) {
    return __uint_as_float(((unsigned int)h) << 16);
}

// ---------------- Phase 1: segment products via split-bf16 MFMA ----------------
// Block (b,s): Q = M_{16s} * ... * M_{16s+15}, built descending: Q <- M_t * Q.
// C-layout == B-frag layout (in-lane identity) -> relayout is a pure bf16 split
// + one LDS exchange. Occupancy experiment: 4 blocks/CU (vs 3 in round 6).
__global__ __launch_bounds__(256, 4)
void seg_kernel(const int* __restrict__ input_ids,
                const float* __restrict__ G_weight,
                float* __restrict__ ws)
{
    __shared__ s8v bexch[2][16][64];   // [pb][kc*4+jb][lane] = {Qh[0..3], Ql[0..3]}

    const int tid = threadIdx.x;
    const int l   = tid & 63;
    const int w   = tid >> 6;     // wave 0..3 = D-row block
    const int g   = l >> 4;
    const int rl  = l & 15;
    const int blk = blockIdx.x;
    const int b   = blk >> 5;
    const int s   = blk & 31;

    // matrices consumed descending; force ids into SGPRs (uniform per block)
    int msq[16];
#pragma unroll
    for (int i = 0; i < 16; ++i)
        msq[i] = __builtin_amdgcn_readfirstlane(
                     input_ids[(b << 9) + (s << 4) + (15 - i)]);

    // acc tile (w,jb): element (16w + 4g + r, 16jb + rl). Init Q = M_last.
    v4f acc[4];
    {
        const float* p0 = G_weight + (((size_t)msq[0]) << 12);
#pragma unroll
        for (int jb = 0; jb < 4; ++jb)
#pragma unroll
            for (int r = 0; r < 4; ++r)
                acc[jb][r] = p0[(((w << 4) + (g << 2) + r) << 6) + (jb << 4) + rl];
    }

    // A-operand rows of M: lane l holds row 16w+rl, cols 16kc+4g..+3 (float4/kc)
    const size_t aoff = (size_t)((((w << 4) + rl) << 6) + (g << 2));
    float4 pA0[4], pA1[4], pA2[4];    // prefetch depth 3 (15 bodies = 3 x 5)

#define ISSUEA(P, IDX) do {                                                \
        const float* gp_ = G_weight + (((size_t)(IDX)) << 12) + aoff;      \
        P[0] = *(const float4*)(gp_);                                      \
        P[1] = *(const float4*)(gp_ + 16);                                 \
        P[2] = *(const float4*)(gp_ + 32);                                 \
        P[3] = *(const float4*)(gp_ + 48);                                 \
    } while (0)

    ISSUEA(pA0, msq[1]);
    ISSUEA(pA1, msq[2]);
    ISSUEA(pA2, msq[3]);

#define SBODY(P, I) do {                                                        \
        const int pb_ = (I) & 1;                                                \
        /* publish Q (=acc) as split B-frags */                                 \
        _Pragma("unroll")                                                       \
        for (int jb = 0; jb < 4; ++jb) {                                        \
            s8v pk;                                                             \
            _Pragma("unroll")                                                   \
            for (int r = 0; r < 4; ++r) {                                       \
                const unsigned short h_ = bf16_rne(acc[jb][r]);                 \
                pk[r]     = (short)h_;                                          \
                pk[4 + r] = (short)bf16_rne(acc[jb][r] - bf16_tof(h_));         \
            }                                                                   \
            bexch[pb_][(w << 2) + jb][l] = pk;                                  \
        }                                                                       \
        /* split prefetched A rows */                                           \
        v4s Ah[4], Al[4];                                                       \
        _Pragma("unroll")                                                       \
        for (int kc = 0; kc < 4; ++kc) {                                        \
            const float e_[4] = {P[kc].x, P[kc].y, P[kc].z, P[kc].w};           \
            _Pragma("unroll")                                                   \
            for (int j = 0; j < 4; ++j) {                                       \
                const unsigned short h_ = bf16_rne(e_[j]);                      \
                Ah[kc][j] = (short)h_;                                          \
                Al[kc][j] = (short)bf16_rne(e_[j] - bf16_tof(h_));              \
            }                                                                   \
        }                                                                       \
        if ((I) + 3 <= 15)                                                      \
            ISSUEA(P, msq[(I) + 3]);                                            \
        asm volatile("s_waitcnt lgkmcnt(0)\n\ts_barrier" ::: "memory");         \
        v4f na[4] = {{0,0,0,0},{0,0,0,0},{0,0,0,0},{0,0,0,0}};                  \
        _Pragma("unroll")                                                       \
        for (int kc = 0; kc < 4; ++kc) {                                        \
            _Pragma("unroll")                                                   \
            for (int jb = 0; jb < 4; ++jb) {                                    \
                const s8v q_ = bexch[pb_][(kc << 2) + jb][l];                   \
                const v4s qh = {q_[0], q_[1], q_[2], q_[3]};                    \
                const v4s ql = {q_[4], q_[5], q_[6], q_[7]};                    \
                na[jb] = mfma16(Ah[kc], qh, na[jb]);                            \
                na[jb] = mfma16(Al[kc], qh, na[jb]);                            \
                na[jb] = mfma16(Ah[kc], ql, na[jb]);                            \
            }                                                                   \
        }                                                                       \
        _Pragma("unroll")                                                       \
        for (int jb = 0; jb < 4; ++jb) acc[jb] = na[jb];                        \
    } while (0)

    SBODY(pA0,  1); SBODY(pA1,  2); SBODY(pA2,  3);
    SBODY(pA0,  4); SBODY(pA1,  5); SBODY(pA2,  6);
    SBODY(pA0,  7); SBODY(pA1,  8); SBODY(pA2,  9);
    SBODY(pA0, 10); SBODY(pA1, 11); SBODY(pA2, 12);
    SBODY(pA0, 13); SBODY(pA1, 14); SBODY(pA2, 15);

    float* wp = ws + (((size_t)blk) << 12);
#pragma unroll
    for (int jb = 0; jb < 4; ++jb)
#pragma unroll
        for (int r = 0; r < 4; ++r)
            wp[(((w << 4) + (g << 2) + r) << 6) + (jb << 4) + rl] = acc[jb][r];
}

// ---------------- Phase 2: 32-step vector chain over segment products ----------------
__device__ __forceinline__ float qreduce4(float x) {
#if __has_builtin(__builtin_amdgcn_permlane16_swap) && __has_builtin(__builtin_amdgcn_permlane32_swap)
    u32x2 a = __builtin_amdgcn_permlane16_swap(__float_as_uint(x), __float_as_uint(x), false, false);
    const float y = __uint_as_float(a.x) + __uint_as_float(a.y);
    u32x2 c = __builtin_amdgcn_permlane32_swap(__float_as_uint(y), __float_as_uint(y), false, false);
    return __uint_as_float(c.x) + __uint_as_float(c.y);
#else
    x += __shfl_xor(x, 16, 64);
    x += __shfl_xor(x, 32, 64);
    return x;
#endif
}

#define STRD 12

__global__ __launch_bounds__(512, 2)
void chain2_kernel(const float* __restrict__ ws,
                   const float* __restrict__ G1_weight,
                   const float* __restrict__ lin_W,
                   const float* __restrict__ lin_b,
                   float* __restrict__ out)
{
    __shared__ __align__(16) float part[2][RDIM][STRD];

    const int tid  = threadIdx.x;
    const int lane = tid & 63;
    const int w    = tid >> 6;
    const int b    = blockIdx.x;
    const int sub  = lane >> 4;
    const int p16  = lane & 15;

    const int k0 = (w << 3) + sub;
    float vm0 = G1_weight[k0];
    float vm1 = G1_weight[k0 + 4];

    const size_t lo0 = (size_t)((w << 9) + (sub << 6) + (p16 << 2));
    const size_t lo1 = lo0 + 256;

    float4 bufA[16], bufB[16];

#define ISSUE2(S, T) do {                                                  \
        const float* bp_ = ws + (((size_t)((b << 5) + (T))) << 12);        \
        bufA[S] = *(const float4*)(bp_ + lo0);                             \
        bufB[S] = *(const float4*)(bp_ + lo1);                             \
    } while (0)

#pragma unroll
    for (int p = 0; p < 16; ++p) ISSUE2(p, p);

#define BODY2(S, T) do {                                                       \
        const float4 a_ = bufA[S];                                             \
        const float4 c_ = bufB[S];                                             \
        float fx = fmaf(vm0, a_.x, vm1 * c_.x);                                \
        float fy = fmaf(vm0, a_.y, vm1 * c_.y);                                \
        float fz = fmaf(vm0, a_.z, vm1 * c_.z);                                \
        float fw = fmaf(vm0, a_.w, vm1 * c_.w);                                \
        { int nx_ = (T) + 16; nx_ = (nx_ < SEGS) ? nx_ : (SEGS - 1);           \
          ISSUE2(S, nx_); }                                                    \
        fx = qreduce4(fx); fy = qreduce4(fy);                                  \
        fz = qreduce4(fz); fw = qreduce4(fw);                                  \
        const float wv_ = (sub == 0) ? fx : (sub == 1) ? fy                    \
                        : (sub == 2) ? fz : fw;                                \
        part[(T) & 1][(p16 << 2) + sub][w] = wv_;                              \
        asm volatile("s_waitcnt lgkmcnt(0)\n\ts_barrier" ::: "memory");        \
        {                                                                      \
            const float4* pk0_ = (const float4*)&part[(T) & 1][k0][0];         \
            const float4  r0_  = pk0_[0], r1_ = pk0_[1];                       \
            vm0 = ((r0_.x + r0_.y) + (r0_.z + r0_.w))                          \
                + ((r1_.x + r1_.y) + (r1_.z + r1_.w));                         \
            const float4* pk1_ = (const float4*)&part[(T) & 1][k0 + 4][0];     \
            const float4  s0_  = pk1_[0], s1_ = pk1_[1];                       \
            vm1 = ((s0_.x + s0_.y) + (s0_.z + s0_.w))                          \
                + ((s1_.x + s1_.y) + (s1_.z + s1_.w));                         \
        }                                                                      \
    } while (0)

    BODY2( 0,  0); BODY2( 1,  1); BODY2( 2,  2); BODY2( 3,  3);
    BODY2( 4,  4); BODY2( 5,  5); BODY2( 6,  6); BODY2( 7,  7);
    BODY2( 8,  8); BODY2( 9,  9); BODY2(10, 10); BODY2(11, 11);
    BODY2(12, 12); BODY2(13, 13); BODY2(14, 14); BODY2(15, 15);
    BODY2( 0, 16); BODY2( 1, 17); BODY2( 2, 18); BODY2( 3, 19);
    BODY2( 4, 20); BODY2( 5, 21); BODY2( 6, 22); BODY2( 7, 23);
    BODY2( 8, 24); BODY2( 9, 25); BODY2(10, 26); BODY2(11, 27);
    BODY2(12, 28); BODY2(13, 29); BODY2(14, 30); BODY2(15, 31);

    asm volatile("s_waitcnt vmcnt(0)" ::: "memory");

    float vj;
    {
        const float4* pj = (const float4*)&part[1][lane][0];
        const float4 q0 = pj[0], q1 = pj[1];
        vj = ((q0.x + q0.y) + (q0.z + q0.w)) + ((q1.x + q1.y) + (q1.z + q1.w));
    }

    if (w == 0) {
        float ss = vj * vj;
#pragma unroll
        for (int off = 32; off >= 1; off >>= 1)
            ss += __shfl_xor(ss, off, 64);
        const float inv = 1.0f / fmaxf(sqrtf(ss), 1e-12f);
        const float nj  = vj * inv;

        float d0 = nj * lin_W[lane];
        float d1 = nj * lin_W[RDIM + lane];
#pragma unroll
        for (int off = 32; off >= 1; off >>= 1) {
            d0 += __shfl_xor(d0, off, 64);
            d1 += __shfl_xor(d1, off, 64);
        }
        if (lane == 0) {
            out[b * 2 + 0] = d0 + lin_b[0];
            out[b * 2 + 1] = d1 + lin_b[1];
        }
    }
}

// ---------------- Fallback: proven round-5 single-kernel chain ----------------
__global__ __launch_bounds__(512, 2)
void matchain_kernel(const int* __restrict__ input_ids,
                     const float* __restrict__ G_weight,
                     const float* __restrict__ G1_weight,
                     const float* __restrict__ lin_W,
                     const float* __restrict__ lin_b,
                     float* __restrict__ out)
{
    __shared__ int   ids[SEQ];
    __shared__ __align__(16) float part[2][RDIM][STRD];

    const int tid  = threadIdx.x;
    const int lane = tid & 63;
    const int w    = tid >> 6;
    const int b    = blockIdx.x;
    const int sub  = lane >> 4;
    const int p16  = lane & 15;

    ids[tid] = input_ids[b * SEQ + tid];
    __syncthreads();

    const int k0 = (w << 3) + sub;
    float vm0 = G1_weight[k0];
    float vm1 = G1_weight[k0 + 4];

    const size_t lo0 = (size_t)((w << 9) + (sub << 6) + (p16 << 2));
    const size_t lo1 = lo0 + 256;

    float4 bufA[16], bufB[16];

#define ISSUE(S, id_) do {                                        \
        const float* bp_ = G_weight + (((size_t)(id_)) << 12);    \
        bufA[S] = *(const float4*)(bp_ + lo0);                    \
        bufB[S] = *(const float4*)(bp_ + lo1);                    \
    } while (0)

#pragma unroll
    for (int p = 0; p < 16; ++p)
        ISSUE(p, __builtin_amdgcn_readfirstlane(ids[p]));

    int pend = ids[16];

#define BODY(S, K) do {                                                        \
        const float4 a_ = bufA[S];                                             \
        const float4 c_ = bufB[S];                                             \
        float fx = fmaf(vm0, a_.x, vm1 * c_.x);                                \
        float fy = fmaf(vm0, a_.y, vm1 * c_.y);                                \
        float fz = fmaf(vm0, a_.z, vm1 * c_.z);                                \
        float fw = fmaf(vm0, a_.w, vm1 * c_.w);                                \
        {                                                                      \
            const int idn_ = __builtin_amdgcn_readfirstlane(pend);             \
            ISSUE(S, idn_);                                                    \
            int nx_ = t0 + (K) + 17;                                           \
            nx_ = (nx_ < SEQ) ? nx_ : (SEQ - 1);                               \
            pend = ids[nx_];                                                   \
        }                                                                      \
        fx = qreduce4(fx); fy = qreduce4(fy);                                  \
        fz = qreduce4(fz); fw = qreduce4(fw);                                  \
        const float wv_ = (sub == 0) ? fx : (sub == 1) ? fy                    \
                        : (sub == 2) ? fz : fw;                                \
        part[(K) & 1][(p16 << 2) + sub][w] = wv_;                              \
        asm volatile("s_waitcnt lgkmcnt(0)\n\ts_barrier" ::: "memory");        \
        {                                                                      \
            const float4* pk0_ = (const float4*)&part[(K) & 1][k0][0];         \
            const float4  r0_  = pk0_[0], r1_ = pk0_[1];                       \
            vm0 = ((r0_.x + r0_.y) + (r0_.z + r0_.w))                          \
                + ((r1_.x + r1_.y) + (r1_.z + r1_.w));                         \
            const float4* pk1_ = (const float4*)&part[(K) & 1][k0 + 4][0];     \
            const float4  s0_  = pk1_[0], s1_ = pk1_[1];                       \
            vm1 = ((s0_.x + s0_.y) + (s0_.z + s0_.w))                          \
                + ((s1_.x + s1_.y) + (s1_.z + s1_.w));                         \
        }                                                                      \
    } while (0)

#pragma unroll 1
    for (int t0 = 0; t0 < SEQ; t0 += 16) {
        BODY( 0,  0); BODY( 1,  1); BODY( 2,  2); BODY( 3,  3);
        BODY( 4,  4); BODY( 5,  5); BODY( 6,  6); BODY( 7,  7);
        BODY( 8,  8); BODY( 9,  9); BODY(10, 10); BODY(11, 11);
        BODY(12, 12); BODY(13, 13); BODY(14, 14); BODY(15, 15);
    }

    asm volatile("s_waitcnt vmcnt(0)" ::: "memory");

    float vj;
    {
        const float4* pj = (const float4*)&part[1][lane][0];
        const float4 q0 = pj[0], q1 = pj[1];
        vj = ((q0.x + q0.y) + (q0.z + q0.w)) + ((q1.x + q1.y) + (q1.z + q1.w));
    }

    if (w == 0) {
        float ss = vj * vj;
#pragma unroll
        for (int off = 32; off >= 1; off >>= 1)
            ss += __shfl_xor(ss, off, 64);
        const float inv = 1.0f / fmaxf(sqrtf(ss), 1e-12f);
        const float nj  = vj * inv;

        float d0 = nj * lin_W[lane];
        float d1 = nj * lin_W[RDIM + lane];
#pragma unroll
        for (int off = 32; off >= 1; off >>= 1) {
            d0 += __shfl_xor(d0, off, 64);
            d1 += __shfl_xor(d1, off, 64);
        }
        if (lane == 0) {
            out[b * 2 + 0] = d0 + lin_b[0];
            out[b * 2 + 1] = d1 + lin_b[1];
        }
    }
}

extern "C" void kernel_launch(void* const* d_in, const int* in_sizes, int n_in,
                              void* d_out, int out_size, void* d_ws, size_t ws_size,
                              hipStream_t stream) {
    const int*   input_ids = (const int*)d_in[0];
    // d_in[1] = mask, d_in[2] = segment_ids, d_in[3] = seq_lengths — unused
    const float* G_weight  = (const float*)d_in[4];
    const float* G1_weight = (const float*)d_in[5];
    const float* lin_W     = (const float*)d_in[6];
    const float* lin_b     = (const float*)d_in[7];
    float*       out       = (float*)d_out;

    const size_t need = (size_t)NB * SEGS * RDIM * RDIM * sizeof(float); // 32 MB
    if (ws_size >= need) {
        float* ws = (float*)d_ws;
        seg_kernel<<<NB * SEGS, 256, 0, stream>>>(input_ids, G_weight, ws);
        chain2_kernel<<<NB, 512, 0, stream>>>(ws, G1_weight, lin_W, lin_b, out);
    } else {
        matchain_kernel<<<NB, 512, 0, stream>>>(input_ids, G_weight, G1_weight,
                                                lin_W, lin_b, out);
    }
}